// Round 7
// baseline (368.519 us; speedup 1.0000x reference)
//
#include <hip/hip_runtime.h>

#define NUM_EMBED 8192
#define DIMC 64
#define HW 4096
#define NQ 32768
#define ZQ_SIZE  2097152
#define LOSS_OFF 2097152
#define IDX_OFF  2097153
#define BIN_OFF  2129921
#define EPS 2.5e-4f

// ws layout (bytes)
#define WS_B      0           // ushort[8192*128]  codes: [ch(64) | cl(64)] per row
#define WS_INV    2097152     // float[8192]       1/max(||ew_k||,1e-12)
#define WS_CNT    2129920     // int               uncertain-count
#define WS_LIST   2129936     // int[32768]        uncertain query list

typedef unsigned int  uint;
typedef unsigned short ushort;
typedef __attribute__((ext_vector_type(8))) short short8;   // bf16x8 MFMA frag
typedef __attribute__((ext_vector_type(4))) float float4_;

__device__ inline ushort f2bf(float f) {            // fp32 -> bf16 RTNE
    uint u = __float_as_uint(f);
    return (ushort)((u + 0x7FFFu + ((u >> 16) & 1u)) >> 16);
}
__device__ inline float bf2f(ushort h) { return __uint_as_float(((uint)h) << 16); }

// --- prep: normalize codebook -> bf16 hi/lo; also zero loss/bins/cnt -------
__global__ __launch_bounds__(256) void vq_prep_b(const float* __restrict__ ew,
        ushort* __restrict__ Bp, float* __restrict__ invn,
        float* __restrict__ out, int* __restrict__ cnt)
{
    const int gi = blockIdx.x * 256 + threadIdx.x;
    if (gi < NUM_EMBED) out[BIN_OFF + gi] = 0.0f;
    if (gi == 0) { out[LOSS_OFF] = 0.0f; *cnt = 0; }

    const int ln  = threadIdx.x & 63;
    const int wv  = threadIdx.x >> 6;
    const int row = blockIdx.x * 4 + wv;
    float v = ew[row * 64 + ln];
    float s = v * v;
    #pragma unroll
    for (int off = 1; off < 64; off <<= 1) s += __shfl_xor(s, off, 64);
    float rinv = 1.0f / fmaxf(sqrtf(s), 1e-12f);
    float cn = v * rinv;
    ushort hi = f2bf(cn);
    ushort lo = f2bf(cn - bf2f(hi));
    Bp[row * 128 + ln]      = hi;
    Bp[row * 128 + 64 + ln] = lo;
    if (ln == 0) invn[row] = rinv;
}

// --- main: split-bf16 MFMA scores, frags direct from L2, fused emit --------
// 1024 blocks x 256 thr (4 waves) -> 4 blocks/CU = 4 waves/SIMD with full
// 128-VGPR budget. Block owns 32 queries (qt=2); wave owns a 16-code column
// of each 64-code tile; 128 tiles. Named register double-buffer, no dynamic
// indexing -> no scratch.
__global__ __launch_bounds__(256, 4) void vq_main(const float* __restrict__ z,
        const ushort* __restrict__ Bp, const float* __restrict__ ew,
        float* __restrict__ out, int* __restrict__ cnt, int* __restrict__ list)
{
    __shared__ __align__(16) ushort qtile[32 * 136];
    __shared__ float msc[4 * 32 * 3];
    __shared__ int   ibuf[32];
    __shared__ int   ubuf[32];
    __shared__ float lred[4];

    const int tid = threadIdx.x;
    const int ln  = tid & 63;
    const int w   = tid >> 6;          // wave 0..3
    const int lm  = ln & 15;
    const int h   = ln >> 4;
    const int h8  = h * 8;

    const int q0  = blockIdx.x * 32;
    const int b   = q0 >> 12;
    const int hw0 = q0 & 4095;

    // build query tile: [q][c]=zh, [q][64+c]=zl  (coalesced z reads)
    {
        const int qr = tid & 31;
        const int cb = (tid >> 5) * 8;     // 8 channel-groups of 8
        const float* zb = z + (size_t)b * (DIMC * HW) + hw0 + qr;
        #pragma unroll
        for (int i = 0; i < 8; ++i) {
            int c = cb + i;
            float f = zb[(size_t)c * HW];
            ushort hi = f2bf(f);
            ushort lo = f2bf(f - bf2f(hi));
            qtile[qr * 136 + c]      = hi;
            qtile[qr * 136 + 64 + c] = lo;
        }
    }
    __syncthreads();

    // query fragments -> registers (constant-indexed only)
    short8 qh0[2], qh1[2], ql0[2], ql1[2];
    #pragma unroll
    for (int qt = 0; qt < 2; ++qt) {
        const ushort* r = &qtile[(qt * 16 + lm) * 136 + h8];
        qh0[qt] = *(const short8*)(r);
        qh1[qt] = *(const short8*)(r + 32);
        ql0[qt] = *(const short8*)(r + 64);
        ql1[qt] = *(const short8*)(r + 96);
    }

    float v1[2], v2[2]; int i1[2];
    #pragma unroll
    for (int qt = 0; qt < 2; ++qt) { v1[qt] = -3e38f; v2[qt] = -3e38f; i1[qt] = 0; }

    // wave's code-fragment rows: (w*16+lm) of each 64-row tile
    const ushort* gp = Bp + (size_t)(w * 16 + lm) * 128 + h8;
    const int wh = w * 16 + h * 4;

    auto compute = [&](short8 ch0, short8 ch1, short8 cl0, short8 cl1, int t) {
        float4_ acc[2];
        #pragma unroll
        for (int qt = 0; qt < 2; ++qt) acc[qt] = (float4_){0.f, 0.f, 0.f, 0.f};
        #pragma unroll
        for (int qt = 0; qt < 2; ++qt) {
            float4_ a = acc[qt];
            a = __builtin_amdgcn_mfma_f32_16x16x32_bf16(ch0, qh0[qt], a, 0, 0, 0);
            a = __builtin_amdgcn_mfma_f32_16x16x32_bf16(ch1, qh1[qt], a, 0, 0, 0);
            a = __builtin_amdgcn_mfma_f32_16x16x32_bf16(cl0, qh0[qt], a, 0, 0, 0);
            a = __builtin_amdgcn_mfma_f32_16x16x32_bf16(cl1, qh1[qt], a, 0, 0, 0);
            a = __builtin_amdgcn_mfma_f32_16x16x32_bf16(ch0, ql0[qt], a, 0, 0, 0);
            a = __builtin_amdgcn_mfma_f32_16x16x32_bf16(ch1, ql1[qt], a, 0, 0, 0);
            acc[qt] = a;
        }
        const int cb2 = t * 64 + wh;     // C/D map: col=lane&15=query, row=h*4+reg
        #pragma unroll
        for (int rr = 0; rr < 4; ++rr) {
            int code = cb2 + rr;
            #pragma unroll
            for (int qt = 0; qt < 2; ++qt) {
                float v = acc[qt][rr];
                // v2 <= v1 invariant: med3(v, v1, v2) == new second-best
                v2[qt] = __builtin_amdgcn_fmed3f(v, v1[qt], v2[qt]);
                bool gt = v > v1[qt];
                v1[qt] = fmaxf(v1[qt], v);
                i1[qt] = gt ? code : i1[qt];
            }
        }
    };

    short8 A0, A1, A2, A3, B0, B1, B2, B3;
#define LDF(d0, d1, d2, d3, T) { const ushort* p = gp + (size_t)(T) * 8192; \
        d0 = *(const short8*)(p);      d1 = *(const short8*)(p + 32);       \
        d2 = *(const short8*)(p + 64); d3 = *(const short8*)(p + 96); }

    LDF(A0, A1, A2, A3, 0)
    #pragma unroll 1
    for (int t = 0; t < 128; t += 2) {
        LDF(B0, B1, B2, B3, t + 1)
        compute(A0, A1, A2, A3, t);
        if (t < 126) LDF(A0, A1, A2, A3, t + 2)
        compute(B0, B1, B2, B3, t + 1);
    }
#undef LDF

    // merge across h-groups (disjoint code rows, same query col)
    #pragma unroll
    for (int m = 16; m <= 32; m <<= 1) {
        #pragma unroll
        for (int qt = 0; qt < 2; ++qt) {
            float ov1 = __shfl_xor(v1[qt], m, 64);
            int   oi1 = __shfl_xor(i1[qt], m, 64);
            float ov2 = __shfl_xor(v2[qt], m, 64);
            float nv2 = fmaxf(fminf(v1[qt], ov1), fmaxf(v2[qt], ov2));
            bool tk = ov1 > v1[qt];
            v1[qt] = tk ? ov1 : v1[qt];
            i1[qt] = tk ? oi1 : i1[qt];
            v2[qt] = nv2;
        }
    }

    if (h == 0) {
        #pragma unroll
        for (int qt = 0; qt < 2; ++qt) {
            int o = (w * 32 + qt * 16 + lm) * 3;
            msc[o] = v1[qt];
            ((int*)msc)[o + 1] = i1[qt];
            msc[o + 2] = v2[qt];
        }
    }
    __syncthreads();
    if (tid < 32) {
        float fv1 = -3e38f, fv2 = -3e38f; int fi = 0;
        #pragma unroll
        for (int wv = 0; wv < 4; ++wv) {
            int o = (wv * 32 + tid) * 3;
            float a1 = msc[o], a2 = msc[o + 2];
            int   ai = ((int*)msc)[o + 1];
            float nv2 = fmaxf(fminf(fv1, a1), fmaxf(fv2, a2));
            bool tk = a1 > fv1;
            fv1 = tk ? a1 : fv1;
            fi  = tk ? ai : fi;
            fv2 = nv2;
        }
        int q = q0 + tid;
        out[IDX_OFF + q] = (float)fi;
        int unc = (fv1 - fv2 <= EPS) ? 1 : 0;
        ibuf[tid] = fi;
        ubuf[tid] = unc;
        if (unc) {
            int s = atomicAdd(cnt, 1);
            list[s] = q;
        } else {
            atomicAdd(&out[BIN_OFF + fi], 1.0f);
        }
    }
    __syncthreads();

    // fused emit for certain queries: z_q scatter + loss (exact z re-read)
    {
        const int qL = tid & 31;
        const int cq = tid >> 5;          // 0..7, 8 channels each
        int fi  = ibuf[qL];
        int unc = ubuf[qL];
        float lsum = 0.f;
        if (!unc) {
            const float4_* wr4 = (const float4_*)(ew + (size_t)fi * 64) + cq * 2;
            const float* zsrc = z   + (size_t)b * (DIMC * HW) + hw0 + qL;
            float*       zq   = out + (size_t)b * (DIMC * HW) + hw0 + qL;
            #pragma unroll
            for (int j = 0; j < 2; ++j) {
                float4_ wv4 = wr4[j];
                #pragma unroll
                for (int e = 0; e < 4; ++e) {
                    int c = cq * 8 + j * 4 + e;
                    float zv = zsrc[(size_t)c * HW];
                    zq[(size_t)c * HW] = wv4[e];
                    float dd = wv4[e] - zv;
                    lsum = fmaf(dd, dd, lsum);
                }
            }
        }
        #pragma unroll
        for (int off = 32; off; off >>= 1) lsum += __shfl_down(lsum, off, 64);
        if (ln == 0) lred[w] = lsum;
    }
    __syncthreads();
    if (tid == 0) {
        float s = lred[0] + lred[1] + lred[2] + lred[3];
        atomicAdd(&out[LOSS_OFF], s * (1.25f / (float)ZQ_SIZE));
    }
}

// --- exact fp32 rescan + emit for uncertain queries ------------------------
__global__ __launch_bounds__(256) void vq_rescan(const float* __restrict__ z,
        const float* __restrict__ ew, const float* __restrict__ invn,
        const int* __restrict__ cnt, const int* __restrict__ list,
        float* __restrict__ out)
{
    __shared__ float zsh[64];
    __shared__ float rbv[4]; __shared__ int rbi[4];
    __shared__ int sfi;
    const int tid = threadIdx.x;
    const int ln  = tid & 63;
    const int wv  = tid >> 6;
    const int n = *cnt;
    for (int u = blockIdx.x; u < n; u += gridDim.x) {
        int q = list[u];
        int b = q >> 12, hw = q & 4095;
        if (tid < 64) zsh[tid] = z[(size_t)b * (DIMC * HW) + (size_t)tid * HW + hw];
        __syncthreads();
        float zf[64];
        #pragma unroll
        for (int c = 0; c < 64; ++c) zf[c] = zsh[c];

        float best = -3e38f; int bi = 0;
        for (int j = 0; j < 32; ++j) {
            int k = j * 256 + tid;                 // coalesced rows
            const float4_* row = (const float4_*)(ew + (size_t)k * 64);
            float a0 = 0.f, a1 = 0.f, a2 = 0.f, a3 = 0.f;
            #pragma unroll
            for (int c4 = 0; c4 < 16; ++c4) {
                float4_ rv = row[c4];
                a0 = fmaf(rv[0], zf[c4 * 4 + 0], a0);
                a1 = fmaf(rv[1], zf[c4 * 4 + 1], a1);
                a2 = fmaf(rv[2], zf[c4 * 4 + 2], a2);
                a3 = fmaf(rv[3], zf[c4 * 4 + 3], a3);
            }
            float d = ((a0 + a1) + (a2 + a3)) * invn[k];
            if (d > best) { best = d; bi = k; }    // per-thread k ascending
        }
        #pragma unroll
        for (int m = 1; m < 64; m <<= 1) {         // first-index tie-break
            float ov = __shfl_xor(best, m, 64);
            int   oi = __shfl_xor(bi, m, 64);
            if (ov > best || (ov == best && oi < bi)) { best = ov; bi = oi; }
        }
        if (ln == 0) { rbv[wv] = best; rbi[wv] = bi; }
        __syncthreads();
        if (tid == 0) {
            float fb = rbv[0]; int fi = rbi[0];
            #pragma unroll
            for (int w2 = 1; w2 < 4; ++w2) {
                if (rbv[w2] > fb || (rbv[w2] == fb && rbi[w2] < fi)) {
                    fb = rbv[w2]; fi = rbi[w2];
                }
            }
            out[IDX_OFF + q] = (float)fi;
            atomicAdd(&out[BIN_OFF + fi], 1.0f);
            sfi = fi;
        }
        __syncthreads();
        // emit z_q row + loss for this query (exact z already in zsh)
        if (tid < 64) {
            int fi = sfi;
            float wvv = ew[(size_t)fi * 64 + tid];
            out[(size_t)b * (DIMC * HW) + (size_t)tid * HW + hw] = wvv;
            float dd = wvv - zsh[tid];
            float lsum = dd * dd;
            #pragma unroll
            for (int off = 32; off; off >>= 1) lsum += __shfl_down(lsum, off, 64);
            if (tid == 0) atomicAdd(&out[LOSS_OFF], lsum * (1.25f / (float)ZQ_SIZE));
        }
        __syncthreads();
    }
}

extern "C" void kernel_launch(void* const* d_in, const int* in_sizes, int n_in,
                              void* d_out, int out_size, void* d_ws, size_t ws_size,
                              hipStream_t stream) {
    const float* z  = (const float*)d_in[0];
    const float* ew = (const float*)d_in[1];
    float* out = (float*)d_out;
    char* ws = (char*)d_ws;
    ushort* Bp  = (ushort*)(ws + WS_B);
    float* invn = (float*)(ws + WS_INV);
    int* cnt    = (int*)(ws + WS_CNT);
    int* list   = (int*)(ws + WS_LIST);

    vq_prep_b<<<NUM_EMBED / 4, 256, 0, stream>>>(ew, Bp, invn, out, cnt);
    vq_main<<<NQ / 32, 256, 0, stream>>>(z, Bp, ew, out, cnt, list);
    vq_rescan<<<4096, 256, 0, stream>>>(z, ew, invn, cnt, list, out);
}

// Round 8
// 265.264 us; speedup vs baseline: 1.3893x; 1.3893x over previous
//
#include <hip/hip_runtime.h>

#define NUM_EMBED 8192
#define DIMC 64
#define HW 4096
#define NQ 32768
#define ZQ_SIZE  2097152
#define LOSS_OFF 2097152
#define IDX_OFF  2097153
#define BIN_OFF  2129921
#define EPS 1.5e-4f

// ws layout (bytes)
#define WS_B      0           // ushort[8192*128]  codes: [ch(64) | cl(64)] per row
#define WS_INV    2097152     // float[8192]       1/max(||ew_k||,1e-12)
#define WS_CNT    2129920     // int               uncertain-count
#define WS_LIST   2129936     // int[32768]        uncertain query list

typedef unsigned int  uint;
typedef unsigned short ushort;
typedef __attribute__((ext_vector_type(8))) short short8;   // bf16x8 MFMA frag
typedef __attribute__((ext_vector_type(4))) float float4_;
typedef __attribute__((ext_vector_type(2))) float float2_;

__device__ inline ushort f2bf(float f) {            // fp32 -> bf16 RTNE
    uint u = __float_as_uint(f);
    return (ushort)((u + 0x7FFFu + ((u >> 16) & 1u)) >> 16);
}
__device__ inline float bf2f(ushort h) { return __uint_as_float(((uint)h) << 16); }

// --- prep: normalize codebook -> bf16 hi/lo; also zero loss/bins/cnt -------
__global__ __launch_bounds__(256) void vq_prep_b(const float* __restrict__ ew,
        ushort* __restrict__ Bp, float* __restrict__ invn,
        float* __restrict__ out, int* __restrict__ cnt)
{
    const int gi = blockIdx.x * 256 + threadIdx.x;
    if (gi < NUM_EMBED) out[BIN_OFF + gi] = 0.0f;
    if (gi == 0) { out[LOSS_OFF] = 0.0f; *cnt = 0; }

    const int ln  = threadIdx.x & 63;
    const int wv  = threadIdx.x >> 6;
    const int row = blockIdx.x * 4 + wv;
    float v = ew[row * 64 + ln];
    float s = v * v;
    #pragma unroll
    for (int off = 1; off < 64; off <<= 1) s += __shfl_xor(s, off, 64);
    float rinv = 1.0f / fmaxf(sqrtf(s), 1e-12f);
    float cn = v * rinv;
    ushort hi = f2bf(cn);
    ushort lo = f2bf(cn - bf2f(hi));
    Bp[row * 128 + ln]      = hi;
    Bp[row * 128 + 64 + ln] = lo;
    if (ln == 0) invn[row] = rinv;
}

// --- main: 4-term split-bf16 MFMA scores (8 indep chains of 4), fused emit -
// R5 config: 512 blocks x 256 thr (4 waves, 2 blocks/CU). Block owns 64
// queries (qt=4); wave owns a 16-code column of each 64-code tile; 128 tiles.
__global__ __launch_bounds__(256, 2) void vq_main(const float* __restrict__ z,
        const ushort* __restrict__ Bp, const float* __restrict__ ew,
        float* __restrict__ out, int* __restrict__ cnt, int* __restrict__ list)
{
    __shared__ __align__(16) ushort qtile[64 * 136];
    __shared__ float msc[4 * 64 * 3];
    __shared__ int   ibuf[64];
    __shared__ int   ubuf[64];
    __shared__ float lred[4];

    const int tid = threadIdx.x;
    const int ln  = tid & 63;
    const int w   = tid >> 6;          // wave 0..3
    const int lm  = ln & 15;
    const int h   = ln >> 4;
    const int h8  = h * 8;

    const int q0  = blockIdx.x * 64;
    const int b   = q0 >> 12;
    const int hw0 = q0 & 4095;

    // build query tile: [q][c]=zh, [q][64+c]=zl  (coalesced z reads)
    {
        const int qr = tid & 63;
        const int cb = (tid >> 6) * 16;
        const float* zb = z + (size_t)b * (DIMC * HW) + hw0 + qr;
        #pragma unroll
        for (int i = 0; i < 16; ++i) {
            int c = cb + i;
            float f = zb[(size_t)c * HW];
            ushort hi = f2bf(f);
            ushort lo = f2bf(f - bf2f(hi));
            qtile[qr * 136 + c]      = hi;
            qtile[qr * 136 + 64 + c] = lo;
        }
    }
    __syncthreads();

    // query fragments -> registers (constant-indexed only)
    short8 qh0[4], qh1[4], ql0[4], ql1[4];
    #pragma unroll
    for (int qt = 0; qt < 4; ++qt) {
        const ushort* r = &qtile[(qt * 16 + lm) * 136 + h8];
        qh0[qt] = *(const short8*)(r);
        qh1[qt] = *(const short8*)(r + 32);
        ql0[qt] = *(const short8*)(r + 64);
        ql1[qt] = *(const short8*)(r + 96);
    }

    float v1[4], v2[4]; int i1[4];
    #pragma unroll
    for (int qt = 0; qt < 4; ++qt) { v1[qt] = -3e38f; v2[qt] = -3e38f; i1[qt] = 0; }

    // wave's code-fragment rows: (w*16+lm) of each 64-row tile
    const ushort* gp = Bp + (size_t)(w * 16 + lm) * 128 + h8;
    const int wh = w * 16 + h * 4;

    auto compute = [&](short8 ch0, short8 ch1, short8 cl0, short8 cl1, int t) {
        float4_ s[4];
        #pragma unroll
        for (int qt = 0; qt < 4; ++qt) {
            // two independent 4-deep chains per qt (full 4-term product)
            float4_ a  = (float4_){0.f, 0.f, 0.f, 0.f};
            float4_ bb = (float4_){0.f, 0.f, 0.f, 0.f};
            a  = __builtin_amdgcn_mfma_f32_16x16x32_bf16(ch0, qh0[qt], a, 0, 0, 0);
            bb = __builtin_amdgcn_mfma_f32_16x16x32_bf16(ch0, ql0[qt], bb, 0, 0, 0);
            a  = __builtin_amdgcn_mfma_f32_16x16x32_bf16(ch1, qh1[qt], a, 0, 0, 0);
            bb = __builtin_amdgcn_mfma_f32_16x16x32_bf16(ch1, ql1[qt], bb, 0, 0, 0);
            a  = __builtin_amdgcn_mfma_f32_16x16x32_bf16(cl0, ql0[qt], a, 0, 0, 0);
            bb = __builtin_amdgcn_mfma_f32_16x16x32_bf16(cl0, qh0[qt], bb, 0, 0, 0);
            a  = __builtin_amdgcn_mfma_f32_16x16x32_bf16(cl1, ql1[qt], a, 0, 0, 0);
            bb = __builtin_amdgcn_mfma_f32_16x16x32_bf16(cl1, qh1[qt], bb, 0, 0, 0);
            s[qt] = a + bb;
        }
        const int cb2 = t * 64 + wh;     // C/D map: col=lane&15=query, row=h*4+reg
        #pragma unroll
        for (int rr = 0; rr < 4; ++rr) {
            int code = cb2 + rr;
            #pragma unroll
            for (int qt = 0; qt < 4; ++qt) {
                float v = s[qt][rr];
                // v2 <= v1 invariant: med3(v, v1, v2) == new second-best
                v2[qt] = __builtin_amdgcn_fmed3f(v, v1[qt], v2[qt]);
                bool gt = v > v1[qt];
                v1[qt] = fmaxf(v1[qt], v);
                i1[qt] = gt ? code : i1[qt];
            }
        }
    };

    short8 A0, A1, A2, A3, B0, B1, B2, B3;
#define LDF(d0, d1, d2, d3, T) { const ushort* p = gp + (size_t)(T) * 8192; \
        d0 = *(const short8*)(p);      d1 = *(const short8*)(p + 32);       \
        d2 = *(const short8*)(p + 64); d3 = *(const short8*)(p + 96); }

    LDF(A0, A1, A2, A3, 0)
    #pragma unroll 1
    for (int t = 0; t < 128; t += 2) {
        LDF(B0, B1, B2, B3, t + 1)
        compute(A0, A1, A2, A3, t);
        if (t < 126) LDF(A0, A1, A2, A3, t + 2)
        compute(B0, B1, B2, B3, t + 1);
    }
#undef LDF

    // merge across h-groups (disjoint code rows, same query col)
    #pragma unroll
    for (int m = 16; m <= 32; m <<= 1) {
        #pragma unroll
        for (int qt = 0; qt < 4; ++qt) {
            float ov1 = __shfl_xor(v1[qt], m, 64);
            int   oi1 = __shfl_xor(i1[qt], m, 64);
            float ov2 = __shfl_xor(v2[qt], m, 64);
            float nv2 = fmaxf(fminf(v1[qt], ov1), fmaxf(v2[qt], ov2));
            bool tk = ov1 > v1[qt];
            v1[qt] = tk ? ov1 : v1[qt];
            i1[qt] = tk ? oi1 : i1[qt];
            v2[qt] = nv2;
        }
    }

    if (h == 0) {
        #pragma unroll
        for (int qt = 0; qt < 4; ++qt) {
            int o = (w * 64 + qt * 16 + lm) * 3;
            msc[o] = v1[qt];
            ((int*)msc)[o + 1] = i1[qt];
            msc[o + 2] = v2[qt];
        }
    }
    __syncthreads();
    if (tid < 64) {
        float fv1 = -3e38f, fv2 = -3e38f; int fi = 0;
        #pragma unroll
        for (int wv = 0; wv < 4; ++wv) {
            int o = (wv * 64 + tid) * 3;
            float a1 = msc[o], a2 = msc[o + 2];
            int   ai = ((int*)msc)[o + 1];
            float nv2 = fmaxf(fminf(fv1, a1), fmaxf(fv2, a2));
            bool tk = a1 > fv1;
            fv1 = tk ? a1 : fv1;
            fi  = tk ? ai : fi;
            fv2 = nv2;
        }
        int q = q0 + tid;
        out[IDX_OFF + q] = (float)fi;
        int unc = (fv1 - fv2 <= EPS) ? 1 : 0;
        ibuf[tid] = fi;
        ubuf[tid] = unc;
        if (unc) {
            int s = atomicAdd(cnt, 1);
            list[s] = q;
        } else {
            atomicAdd(&out[BIN_OFF + fi], 1.0f);
        }
    }
    __syncthreads();

    // fused emit for certain queries: z_q scatter + loss (exact z re-read)
    {
        const int qL = tid & 63;
        const int cq = tid >> 6;
        int fi  = ibuf[qL];
        int unc = ubuf[qL];
        float lsum = 0.f;
        if (!unc) {
            const float4_* wr4 = (const float4_*)(ew + (size_t)fi * 64) + cq * 4;
            const float* zsrc = z   + (size_t)b * (DIMC * HW) + hw0 + qL;
            float*       zq   = out + (size_t)b * (DIMC * HW) + hw0 + qL;
            #pragma unroll
            for (int j = 0; j < 4; ++j) {
                float4_ wv4 = wr4[j];
                #pragma unroll
                for (int e = 0; e < 4; ++e) {
                    int c = cq * 16 + j * 4 + e;
                    float zv = zsrc[(size_t)c * HW];
                    zq[(size_t)c * HW] = wv4[e];
                    float dd = wv4[e] - zv;
                    lsum = fmaf(dd, dd, lsum);
                }
            }
        }
        #pragma unroll
        for (int off = 32; off; off >>= 1) lsum += __shfl_down(lsum, off, 64);
        if (ln == 0) lred[w] = lsum;
    }
    __syncthreads();
    if (tid == 0) {
        float s = lred[0] + lred[1] + lred[2] + lred[3];
        atomicAdd(&out[LOSS_OFF], s * (1.25f / (float)ZQ_SIZE));
    }
}

// --- exact fp32 rescan + emit, LDS-coalesced (fixes uncoalesced row reads) -
// One 256-thr block per uncertain query; 64 rounds of 128 rows staged into
// padded LDS via coalesced float2 loads; 2 threads per row from LDS.
__global__ __launch_bounds__(256) void vq_rescan(const float* __restrict__ z,
        const float* __restrict__ ew, const float* __restrict__ invn,
        const int* __restrict__ cnt, const int* __restrict__ list,
        float* __restrict__ out)
{
    __shared__ float zsh[64];
    __shared__ float tile[128 * 66];   // rows padded to 66 floats (33.8 KB)
    __shared__ float rbv[4]; __shared__ int rbi[4];
    __shared__ int sfi;
    const int tid  = threadIdx.x;
    const int ln   = tid & 63;
    const int wv   = tid >> 6;
    const int row  = tid >> 1;         // 0..127
    const int half = (tid & 1) * 32;   // 0 or 32
    const int n = *cnt;
    for (int u = blockIdx.x; u < n; u += gridDim.x) {
        int q = list[u];
        int b = q >> 12, hw = q & 4095;
        if (tid < 64) zsh[tid] = z[(size_t)b * (DIMC * HW) + (size_t)tid * HW + hw];
        __syncthreads();

        float best = -3e38f; int bi = 0;
        for (int rb = 0; rb < NUM_EMBED; rb += 128) {
            // stage 128 rows coalesced: 4096 float2, 16 per thread
            const float2_* g = (const float2_*)(ew + (size_t)rb * 64);
            #pragma unroll
            for (int i = 0; i < 16; ++i) {
                int idx = i * 256 + tid;       // float2 index
                int e = idx * 2;
                int r = e >> 6, c = e & 63;
                *(float2_*)&tile[r * 66 + c] = g[idx];
            }
            __syncthreads();
            // dot: 2 threads per row, 32 elements each
            float a0 = 0.f, a1 = 0.f;
            #pragma unroll
            for (int e = 0; e < 32; e += 2) {
                a0 = fmaf(tile[row * 66 + half + e],     zsh[half + e],     a0);
                a1 = fmaf(tile[row * 66 + half + e + 1], zsh[half + e + 1], a1);
            }
            float part = a0 + a1;
            float full = part + __shfl_xor(part, 1, 64);
            int k = rb + row;
            float d = full * invn[k];
            if (d > best) { best = d; bi = k; }   // k ascending per thread
            __syncthreads();
        }
        // reduce across wave (dup pairs hold identical values -> harmless)
        #pragma unroll
        for (int m = 1; m < 64; m <<= 1) {
            float ov = __shfl_xor(best, m, 64);
            int   oi = __shfl_xor(bi, m, 64);
            if (ov > best || (ov == best && oi < bi)) { best = ov; bi = oi; }
        }
        if (ln == 0) { rbv[wv] = best; rbi[wv] = bi; }
        __syncthreads();
        if (tid == 0) {
            float fb = rbv[0]; int fi = rbi[0];
            #pragma unroll
            for (int w2 = 1; w2 < 4; ++w2) {
                if (rbv[w2] > fb || (rbv[w2] == fb && rbi[w2] < fi)) {
                    fb = rbv[w2]; fi = rbi[w2];
                }
            }
            out[IDX_OFF + q] = (float)fi;
            atomicAdd(&out[BIN_OFF + fi], 1.0f);
            sfi = fi;
        }
        __syncthreads();
        // emit z_q row + loss for this query (exact z already in zsh)
        if (tid < 64) {
            int fi = sfi;
            float wvv = ew[(size_t)fi * 64 + tid];
            out[(size_t)b * (DIMC * HW) + (size_t)tid * HW + hw] = wvv;
            float dd = wvv - zsh[tid];
            float lsum = dd * dd;
            #pragma unroll
            for (int off = 32; off; off >>= 1) lsum += __shfl_down(lsum, off, 64);
            if (tid == 0) atomicAdd(&out[LOSS_OFF], lsum * (1.25f / (float)ZQ_SIZE));
        }
        __syncthreads();
    }
}

extern "C" void kernel_launch(void* const* d_in, const int* in_sizes, int n_in,
                              void* d_out, int out_size, void* d_ws, size_t ws_size,
                              hipStream_t stream) {
    const float* z  = (const float*)d_in[0];
    const float* ew = (const float*)d_in[1];
    float* out = (float*)d_out;
    char* ws = (char*)d_ws;
    ushort* Bp  = (ushort*)(ws + WS_B);
    float* invn = (float*)(ws + WS_INV);
    int* cnt    = (int*)(ws + WS_CNT);
    int* list   = (int*)(ws + WS_LIST);

    vq_prep_b<<<NUM_EMBED / 4, 256, 0, stream>>>(ew, Bp, invn, out, cnt);
    vq_main<<<NQ / 64, 256, 0, stream>>>(z, Bp, ew, out, cnt, list);
    vq_rescan<<<1024, 256, 0, stream>>>(z, ew, invn, cnt, list, out);
}

// Round 9
// 202.573 us; speedup vs baseline: 1.8192x; 1.3095x over previous
//
#include <hip/hip_runtime.h>

#define NUM_EMBED 8192
#define DIMC 64
#define HW 4096
#define NQ 32768
#define ZQ_SIZE  2097152
#define LOSS_OFF 2097152
#define IDX_OFF  2097153
#define BIN_OFF  2129921
#define EPS 1.5e-4f

// ws layout (bytes)
#define WS_B      0           // ushort[8192*128]  codes: [ch(64) | cl(64)] per row
#define WS_INV    2097152     // float[8192]       1/max(||ew_k||,1e-12)
#define WS_CNT    2129920     // int               uncertain-count
#define WS_LIST   2129936     // int[32768]        uncertain query list
#define WS_PART   2261008     // float2[cap*16]    rescan partials (val, idx)

typedef unsigned int  uint;
typedef unsigned short ushort;
typedef __attribute__((ext_vector_type(8))) short short8;   // bf16x8 MFMA frag
typedef __attribute__((ext_vector_type(4))) float float4_;
typedef __attribute__((ext_vector_type(2))) float float2_;

__device__ inline ushort f2bf(float f) {            // fp32 -> bf16 RTNE
    uint u = __float_as_uint(f);
    return (ushort)((u + 0x7FFFu + ((u >> 16) & 1u)) >> 16);
}
__device__ inline float bf2f(ushort h) { return __uint_as_float(((uint)h) << 16); }

// --- prep: normalize codebook -> bf16 hi/lo; also zero loss/bins/cnt -------
__global__ __launch_bounds__(256) void vq_prep_b(const float* __restrict__ ew,
        ushort* __restrict__ Bp, float* __restrict__ invn,
        float* __restrict__ out, int* __restrict__ cnt)
{
    const int gi = blockIdx.x * 256 + threadIdx.x;
    if (gi < NUM_EMBED) out[BIN_OFF + gi] = 0.0f;
    if (gi == 0) { out[LOSS_OFF] = 0.0f; *cnt = 0; }

    const int ln  = threadIdx.x & 63;
    const int wv  = threadIdx.x >> 6;
    const int row = blockIdx.x * 4 + wv;
    float v = ew[row * 64 + ln];
    float s = v * v;
    #pragma unroll
    for (int off = 1; off < 64; off <<= 1) s += __shfl_xor(s, off, 64);
    float rinv = 1.0f / fmaxf(sqrtf(s), 1e-12f);
    float cn = v * rinv;
    ushort hi = f2bf(cn);
    ushort lo = f2bf(cn - bf2f(hi));
    Bp[row * 128 + ln]      = hi;
    Bp[row * 128 + 64 + ln] = lo;
    if (ln == 0) invn[row] = rinv;
}

// --- main: 4-term split-bf16 MFMA scores (8 indep chains of 4), fused emit -
// (byte-identical to R8's proven 145 us kernel)
__global__ __launch_bounds__(256, 2) void vq_main(const float* __restrict__ z,
        const ushort* __restrict__ Bp, const float* __restrict__ ew,
        float* __restrict__ out, int* __restrict__ cnt, int* __restrict__ list)
{
    __shared__ __align__(16) ushort qtile[64 * 136];
    __shared__ float msc[4 * 64 * 3];
    __shared__ int   ibuf[64];
    __shared__ int   ubuf[64];
    __shared__ float lred[4];

    const int tid = threadIdx.x;
    const int ln  = tid & 63;
    const int w   = tid >> 6;          // wave 0..3
    const int lm  = ln & 15;
    const int h   = ln >> 4;
    const int h8  = h * 8;

    const int q0  = blockIdx.x * 64;
    const int b   = q0 >> 12;
    const int hw0 = q0 & 4095;

    // build query tile: [q][c]=zh, [q][64+c]=zl  (coalesced z reads)
    {
        const int qr = tid & 63;
        const int cb = (tid >> 6) * 16;
        const float* zb = z + (size_t)b * (DIMC * HW) + hw0 + qr;
        #pragma unroll
        for (int i = 0; i < 16; ++i) {
            int c = cb + i;
            float f = zb[(size_t)c * HW];
            ushort hi = f2bf(f);
            ushort lo = f2bf(f - bf2f(hi));
            qtile[qr * 136 + c]      = hi;
            qtile[qr * 136 + 64 + c] = lo;
        }
    }
    __syncthreads();

    // query fragments -> registers (constant-indexed only)
    short8 qh0[4], qh1[4], ql0[4], ql1[4];
    #pragma unroll
    for (int qt = 0; qt < 4; ++qt) {
        const ushort* r = &qtile[(qt * 16 + lm) * 136 + h8];
        qh0[qt] = *(const short8*)(r);
        qh1[qt] = *(const short8*)(r + 32);
        ql0[qt] = *(const short8*)(r + 64);
        ql1[qt] = *(const short8*)(r + 96);
    }

    float v1[4], v2[4]; int i1[4];
    #pragma unroll
    for (int qt = 0; qt < 4; ++qt) { v1[qt] = -3e38f; v2[qt] = -3e38f; i1[qt] = 0; }

    // wave's code-fragment rows: (w*16+lm) of each 64-row tile
    const ushort* gp = Bp + (size_t)(w * 16 + lm) * 128 + h8;
    const int wh = w * 16 + h * 4;

    auto compute = [&](short8 ch0, short8 ch1, short8 cl0, short8 cl1, int t) {
        float4_ s[4];
        #pragma unroll
        for (int qt = 0; qt < 4; ++qt) {
            // two independent 4-deep chains per qt (full 4-term product)
            float4_ a  = (float4_){0.f, 0.f, 0.f, 0.f};
            float4_ bb = (float4_){0.f, 0.f, 0.f, 0.f};
            a  = __builtin_amdgcn_mfma_f32_16x16x32_bf16(ch0, qh0[qt], a, 0, 0, 0);
            bb = __builtin_amdgcn_mfma_f32_16x16x32_bf16(ch0, ql0[qt], bb, 0, 0, 0);
            a  = __builtin_amdgcn_mfma_f32_16x16x32_bf16(ch1, qh1[qt], a, 0, 0, 0);
            bb = __builtin_amdgcn_mfma_f32_16x16x32_bf16(ch1, ql1[qt], bb, 0, 0, 0);
            a  = __builtin_amdgcn_mfma_f32_16x16x32_bf16(cl0, ql0[qt], a, 0, 0, 0);
            bb = __builtin_amdgcn_mfma_f32_16x16x32_bf16(cl0, qh0[qt], bb, 0, 0, 0);
            a  = __builtin_amdgcn_mfma_f32_16x16x32_bf16(cl1, ql1[qt], a, 0, 0, 0);
            bb = __builtin_amdgcn_mfma_f32_16x16x32_bf16(cl1, qh1[qt], bb, 0, 0, 0);
            s[qt] = a + bb;
        }
        const int cb2 = t * 64 + wh;     // C/D map: col=lane&15=query, row=h*4+reg
        #pragma unroll
        for (int rr = 0; rr < 4; ++rr) {
            int code = cb2 + rr;
            #pragma unroll
            for (int qt = 0; qt < 4; ++qt) {
                float v = s[qt][rr];
                v2[qt] = __builtin_amdgcn_fmed3f(v, v1[qt], v2[qt]);
                bool gt = v > v1[qt];
                v1[qt] = fmaxf(v1[qt], v);
                i1[qt] = gt ? code : i1[qt];
            }
        }
    };

    short8 A0, A1, A2, A3, B0, B1, B2, B3;
#define LDF(d0, d1, d2, d3, T) { const ushort* p = gp + (size_t)(T) * 8192; \
        d0 = *(const short8*)(p);      d1 = *(const short8*)(p + 32);       \
        d2 = *(const short8*)(p + 64); d3 = *(const short8*)(p + 96); }

    LDF(A0, A1, A2, A3, 0)
    #pragma unroll 1
    for (int t = 0; t < 128; t += 2) {
        LDF(B0, B1, B2, B3, t + 1)
        compute(A0, A1, A2, A3, t);
        if (t < 126) LDF(A0, A1, A2, A3, t + 2)
        compute(B0, B1, B2, B3, t + 1);
    }
#undef LDF

    // merge across h-groups (disjoint code rows, same query col)
    #pragma unroll
    for (int m = 16; m <= 32; m <<= 1) {
        #pragma unroll
        for (int qt = 0; qt < 4; ++qt) {
            float ov1 = __shfl_xor(v1[qt], m, 64);
            int   oi1 = __shfl_xor(i1[qt], m, 64);
            float ov2 = __shfl_xor(v2[qt], m, 64);
            float nv2 = fmaxf(fminf(v1[qt], ov1), fmaxf(v2[qt], ov2));
            bool tk = ov1 > v1[qt];
            v1[qt] = tk ? ov1 : v1[qt];
            i1[qt] = tk ? oi1 : i1[qt];
            v2[qt] = nv2;
        }
    }

    if (h == 0) {
        #pragma unroll
        for (int qt = 0; qt < 4; ++qt) {
            int o = (w * 64 + qt * 16 + lm) * 3;
            msc[o] = v1[qt];
            ((int*)msc)[o + 1] = i1[qt];
            msc[o + 2] = v2[qt];
        }
    }
    __syncthreads();
    if (tid < 64) {
        float fv1 = -3e38f, fv2 = -3e38f; int fi = 0;
        #pragma unroll
        for (int wv = 0; wv < 4; ++wv) {
            int o = (wv * 64 + tid) * 3;
            float a1 = msc[o], a2 = msc[o + 2];
            int   ai = ((int*)msc)[o + 1];
            float nv2 = fmaxf(fminf(fv1, a1), fmaxf(fv2, a2));
            bool tk = a1 > fv1;
            fv1 = tk ? a1 : fv1;
            fi  = tk ? ai : fi;
            fv2 = nv2;
        }
        int q = q0 + tid;
        out[IDX_OFF + q] = (float)fi;
        int unc = (fv1 - fv2 <= EPS) ? 1 : 0;
        ibuf[tid] = fi;
        ubuf[tid] = unc;
        if (unc) {
            int s = atomicAdd(cnt, 1);
            list[s] = q;
        } else {
            atomicAdd(&out[BIN_OFF + fi], 1.0f);
        }
    }
    __syncthreads();

    // fused emit for certain queries: z_q scatter + loss (exact z re-read)
    {
        const int qL = tid & 63;
        const int cq = tid >> 6;
        int fi  = ibuf[qL];
        int unc = ubuf[qL];
        float lsum = 0.f;
        if (!unc) {
            const float4_* wr4 = (const float4_*)(ew + (size_t)fi * 64) + cq * 4;
            const float* zsrc = z   + (size_t)b * (DIMC * HW) + hw0 + qL;
            float*       zq   = out + (size_t)b * (DIMC * HW) + hw0 + qL;
            #pragma unroll
            for (int j = 0; j < 4; ++j) {
                float4_ wv4 = wr4[j];
                #pragma unroll
                for (int e = 0; e < 4; ++e) {
                    int c = cq * 16 + j * 4 + e;
                    float zv = zsrc[(size_t)c * HW];
                    zq[(size_t)c * HW] = wv4[e];
                    float dd = wv4[e] - zv;
                    lsum = fmaf(dd, dd, lsum);
                }
            }
        }
        #pragma unroll
        for (int off = 32; off; off >>= 1) lsum += __shfl_down(lsum, off, 64);
        if (ln == 0) lred[w] = lsum;
    }
    __syncthreads();
    if (tid == 0) {
        float s = lred[0] + lred[1] + lred[2] + lred[3];
        atomicAdd(&out[LOSS_OFF], s * (1.25f / (float)ZQ_SIZE));
    }
}

// --- rescan stage A: 16 blocks per uncertain query, 512 codes each ---------
// Parallelizes the per-query exact scan so wall time is ~one 128KB chunk.
__global__ __launch_bounds__(256) void vq_rescan_a(const float* __restrict__ z,
        const float* __restrict__ ew, const float* __restrict__ invn,
        const int* __restrict__ cnt, const int* __restrict__ list,
        float2_* __restrict__ part, int cap)
{
    __shared__ float zsh[64];
    __shared__ float wbv[4]; __shared__ int wbi[4];
    const int tid   = threadIdx.x;
    const int ln    = tid & 63;
    const int wv    = tid >> 6;
    const int chunk = blockIdx.x & 15;
    const int n = *cnt;
    const int nc = (n < cap) ? n : cap;
    for (int u = blockIdx.x >> 4; u < nc; u += 256) {
        int q = list[u];
        int b = q >> 12, hw = q & 4095;
        if (tid < 64) zsh[tid] = z[(size_t)b * (DIMC * HW) + (size_t)tid * HW + hw];
        __syncthreads();

        const int k1 = chunk * 512 + tid;
        const int k2 = k1 + 256;
        const float4_* r1 = (const float4_*)(ew + (size_t)k1 * 64);
        const float4_* r2 = (const float4_*)(ew + (size_t)k2 * 64);
        float a0 = 0.f, a1 = 0.f, b0 = 0.f, b1 = 0.f;
        #pragma unroll
        for (int c4 = 0; c4 < 16; ++c4) {
            float4_ va = r1[c4], vb = r2[c4];
            float z0 = zsh[c4 * 4 + 0], z1 = zsh[c4 * 4 + 1];
            float z2 = zsh[c4 * 4 + 2], z3 = zsh[c4 * 4 + 3];
            a0 = fmaf(va[0], z0, a0); a1 = fmaf(va[1], z1, a1);
            a0 = fmaf(va[2], z2, a0); a1 = fmaf(va[3], z3, a1);
            b0 = fmaf(vb[0], z0, b0); b1 = fmaf(vb[1], z1, b1);
            b0 = fmaf(vb[2], z2, b0); b1 = fmaf(vb[3], z3, b1);
        }
        float d1 = (a0 + a1) * invn[k1];
        float d2 = (b0 + b1) * invn[k2];
        float bv = (d1 >= d2) ? d1 : d2;     // prefer lower k on tie
        int   bk = (d1 >= d2) ? k1 : k2;
        #pragma unroll
        for (int m = 1; m < 64; m <<= 1) {   // lowest-index tie-break
            float ov = __shfl_xor(bv, m, 64);
            int   oi = __shfl_xor(bk, m, 64);
            if (ov > bv || (ov == bv && oi < bk)) { bv = ov; bk = oi; }
        }
        if (ln == 0) { wbv[wv] = bv; wbi[wv] = bk; }
        __syncthreads();
        if (tid == 0) {
            float fb = wbv[0]; int fi = wbi[0];
            #pragma unroll
            for (int w2 = 1; w2 < 4; ++w2) {
                if (wbv[w2] > fb || (wbv[w2] == fb && wbi[w2] < fi)) {
                    fb = wbv[w2]; fi = wbi[w2];
                }
            }
            float2_ p; p[0] = fb; p[1] = __int_as_float(fi);
            part[u * 16 + chunk] = p;
        }
        __syncthreads();
    }
}

// --- rescan stage B: merge 16 partials per query + emit --------------------
__global__ __launch_bounds__(64) void vq_rescan_b(const float* __restrict__ z,
        const float* __restrict__ ew, const float* __restrict__ invn,
        const int* __restrict__ cnt, const int* __restrict__ list,
        const float2_* __restrict__ part, int cap, float* __restrict__ out)
{
    __shared__ float zsh[64];
    __shared__ int sfi;
    const int tid = threadIdx.x;
    const int n = *cnt;
    for (int u = blockIdx.x; u < n; u += gridDim.x) {
        int q = list[u];
        int b = q >> 12, hw = q & 4095;
        zsh[tid] = z[(size_t)b * (DIMC * HW) + (size_t)tid * HW + hw];
        __syncthreads();
        if (tid == 0) {
            float fb = -3e38f; int fi = 0;
            if (u < cap) {
                for (int c = 0; c < 16; ++c) {       // ascending chunk = asc k
                    float2_ p = part[u * 16 + c];
                    float pv = p[0]; int pk = __float_as_int(p[1]);
                    if (pv > fb || (pv == fb && pk < fi)) { fb = pv; fi = pk; }
                }
            } else {                                  // overflow fallback
                for (int k = 0; k < NUM_EMBED; ++k) {
                    const float* row = ew + (size_t)k * 64;
                    float s = 0.f;
                    for (int c = 0; c < 64; ++c) s = fmaf(row[c], zsh[c], s);
                    s *= invn[k];
                    if (s > fb) { fb = s; fi = k; }
                }
            }
            out[IDX_OFF + q] = (float)fi;
            atomicAdd(&out[BIN_OFF + fi], 1.0f);
            sfi = fi;
        }
        __syncthreads();
        {
            int fi = sfi;
            float wvv = ew[(size_t)fi * 64 + tid];
            out[(size_t)b * (DIMC * HW) + (size_t)tid * HW + hw] = wvv;
            float dd = wvv - zsh[tid];
            float lsum = dd * dd;
            #pragma unroll
            for (int off = 32; off; off >>= 1) lsum += __shfl_down(lsum, off, 64);
            if (tid == 0) atomicAdd(&out[LOSS_OFF], lsum * (1.25f / (float)ZQ_SIZE));
        }
        __syncthreads();
    }
}

extern "C" void kernel_launch(void* const* d_in, const int* in_sizes, int n_in,
                              void* d_out, int out_size, void* d_ws, size_t ws_size,
                              hipStream_t stream) {
    const float* z  = (const float*)d_in[0];
    const float* ew = (const float*)d_in[1];
    float* out = (float*)d_out;
    char* ws = (char*)d_ws;
    ushort* Bp    = (ushort*)(ws + WS_B);
    float* invn   = (float*)(ws + WS_INV);
    int* cnt      = (int*)(ws + WS_CNT);
    int* list     = (int*)(ws + WS_LIST);
    float2_* part = (float2_*)(ws + WS_PART);
    // capacity for partials, bounded by actual ws_size (host-constant branch)
    int cap = 0;
    if (ws_size > WS_PART + 128) {
        size_t avail = (ws_size - WS_PART) / (16 * sizeof(float2_));
        cap = (int)(avail < 4096 ? avail : 4096);
    }

    vq_prep_b<<<NUM_EMBED / 4, 256, 0, stream>>>(ew, Bp, invn, out, cnt);
    vq_main<<<NQ / 64, 256, 0, stream>>>(z, Bp, ew, out, cnt, list);
    vq_rescan_a<<<4096, 256, 0, stream>>>(z, ew, invn, cnt, list, part, cap);
    vq_rescan_b<<<2048, 64, 0, stream>>>(z, ew, invn, cnt, list, part, cap, out);
}